// Round 12
// baseline (285.932 us; speedup 1.0000x reference)
//
#include <hip/hip_runtime.h>

using u16 = unsigned short;
using u32 = unsigned int;

typedef __bf16 bf16x8 __attribute__((ext_vector_type(8)));
typedef float  f32x4  __attribute__((ext_vector_type(4)));

#define NPOS   225          // 15*15 valid positions
#define NT     15           // row-tiles; wave w owns tiles {2w, 2w+1} (w<7), wave 7 owns {14}
#define ROWP   136          // padded LDS row stride in ushorts (272B)
#define A_ROWS 289          // 17*17 haloed positions
#define A_ELEMS (A_ROWS*ROWP)            // 39304 u16
#define LDS_BYTES ((A_ELEMS + 1024)*2)   // 80656 B -> 2 blocks/CU possible
#define RSTRIDE17 (17*ROWP)              // 2312

// ---- workspace layout ----
// floats [0..768): dconv0 weights [k=c*3+t][s_o] (stored-order o); [768..896): dconv0 bias (stored)
// bf16 (u16) region, offsets in u16 units:
#define WA_PER_L 49152      // per dconv layer: [tap 3][kb 4][ot 8][lane 64][8]
#define WP_OFF   (4*WA_PER_L)          // 196608 ; 6 x [kb 4][ot 8][lane 64][8]
#define WP_PER   16384
#define WF_OFF   (WP_OFF + 6*WP_PER)   // 294912 ; [kb 4][ot 4][lane 64][8]
#define W_U16_TOTAL (WF_OFF + 8192)    // 303104

// storage<->logical channel permutation: swap bits[5:4] and [3:2]; self-inverse
__host__ __device__ __forceinline__ int permc(int c){
  return (c & ~0x3C) | (((c >> 2) & 3) << 4) | (((c >> 4) & 3) << 2);
}

__device__ __forceinline__ float bflo(u32 q){ return __uint_as_float(q << 16); }
__device__ __forceinline__ float bfhi(u32 q){ return __uint_as_float(q & 0xffff0000u); }
__device__ __forceinline__ u16 f2bf(float f){
  u32 u = __float_as_uint(f);
  return (u16)((u + 0x7fffu + ((u >> 16) & 1u)) >> 16);   // RNE (prep kernel only)
}
__device__ __forceinline__ u32 packbf(float a, float b){
  union { __bf16 h[2]; u32 u; } r;
  r.h[0] = (__bf16)a; r.h[1] = (__bf16)b;
  return r.u;
}
__device__ __forceinline__ float silu_f(float x){
  return x * __builtin_amdgcn_rcpf(1.f + __expf(-x));
}
__device__ __forceinline__ f32x4 mfma16(bf16x8 a, bf16x8 b, f32x4 c){
  return __builtin_amdgcn_mfma_f32_16x16x32_bf16(a, b, c, 0, 0, 0);
}
__device__ __forceinline__ uint4 pack_silu2(const f32x4& a, const f32x4& b){
  uint4 q;
  q.x = packbf(silu_f(a[0]), silu_f(a[1]));
  q.y = packbf(silu_f(a[2]), silu_f(a[3]));
  q.z = packbf(silu_f(b[0]), silu_f(b[1]));
  q.w = packbf(silu_f(b[2]), silu_f(b[3]));
  return q;
}
__device__ __forceinline__ uint4 silu_add4(const f32x4& a, const f32x4& b, const uint4& r){
  uint4 q;
  q.x = packbf(silu_f(a[0]) + bflo(r.x), silu_f(a[1]) + bfhi(r.x));
  q.y = packbf(silu_f(a[2]) + bflo(r.y), silu_f(a[3]) + bfhi(r.y));
  q.z = packbf(silu_f(b[0]) + bflo(r.z), silu_f(b[1]) + bfhi(r.z));
  q.w = packbf(silu_f(b[2]) + bflo(r.w), silu_f(b[3]) + bfhi(r.w));
  return q;
}

// ---- weight prep ----
__global__ void prep_w(const float* __restrict__ d0w, const float* __restrict__ d0b,
                       const float* __restrict__ rdw,
                       const float* __restrict__ rpw, const float* __restrict__ c1w,
                       const float* __restrict__ c2w, const float* __restrict__ fw,
                       float* __restrict__ ws)
{
  u16* wsb = (u16*)(ws + 896);
  const int total = 896 + W_U16_TOTAL;
  for (int idx = blockIdx.x*blockDim.x + threadIdx.x; idx < total; idx += gridDim.x*blockDim.x){
    if (idx < 768){                      // dconv0: ws[k*128+s] = w[perm(s)][k]
      int k = idx >> 7, s = idx & 127;
      ws[idx] = d0w[permc(s)*6 + k];
      continue;
    }
    if (idx < 896){
      int s = idx - 768;
      ws[idx] = d0b[permc(s)];
      continue;
    }
    int e = idx - 896;
    float v;
    if (e < WP_OFF){                     // dconv frags [L][tap][kb][ot8][l][j]
      int L = e / WA_PER_L, r = e % WA_PER_L;
      int tap = r / 16384, r1 = r % 16384;
      int kb = r1 >> 12, ot = (r1 >> 9) & 7, l = (r1 >> 3) & 63, j = r1 & 7;
      int o = ot*16 + (l & 15);
      int ks = kb*32 + ((l >> 4) << 3) + j;
      v = rdw[((L*128 + o)*128 + permc(ks))*3 + tap];
    } else if (e < WF_OFF){              // pw frags [i6][kb][ot8][l][j]
      int t2 = e - WP_OFF;
      int i = t2 / WP_PER, r = t2 % WP_PER;
      int kb = r >> 12, ot = (r >> 9) & 7, l = (r >> 3) & 63, j = r & 7;
      int o = ot*16 + (l & 15);
      int ks = kb*32 + ((l >> 4) << 3) + j;
      v = (i < 4) ? rpw[(i*128 + o)*128 + permc(ks)]
        : (i == 4) ? c1w[o*128 + permc(ks)] : c2w[o*128 + permc(ks)];
    } else {                             // final frags [kb][ot4][l][j]
      int e2 = e - WF_OFF;
      int kb = e2 >> 11, ot = (e2 >> 9) & 3, l = (e2 >> 3) & 63, j = e2 & 7;
      int o = ot*16 + (l & 15);
      int ks = kb*32 + ((l >> 4) << 3) + j;
      v = fw[o*128 + permc(ks)];
    }
    wsb[e] = f2bf(v);
  }
}

// ---- dconv 128->128: accumulate all 8 o-tiles for NTL tiles; no writes ----
template<int NTL>
__device__ __forceinline__ void dconv_phase(f32x4 (&acc)[8][2],
    const u16* __restrict__ As, const u16* __restrict__ wd,
    const float* __restrict__ bd, int lane, int T0, int dr0, int dr2)
{
  const int col = lane & 15, kg = lane >> 4;
  #pragma unroll
  for (int ot=0; ot<8; ++ot){
    f32x4 bz = *(const f32x4*)(bd + ot*16 + kg*4);
    #pragma unroll
    for (int t=0;t<NTL;++t) acc[ot][t] = bz;
  }
  const int rb0 = ((T0+1)*17 + col + 1)*ROWP + kg*8;
  #pragma unroll 1
  for (int tap=0; tap<3; ++tap){
    const int offr = ((tap==0) ? dr0 : (tap==1) ? 0 : dr2)*ROWP;
    #pragma unroll 1
    for (int kb=0; kb<4; ++kb){
      bf16x8 w[8];
      #pragma unroll
      for (int ot=0; ot<8; ++ot)
        w[ot] = *(const bf16x8*)(wd + ((tap*4+kb)*8 + ot)*512 + lane*8);
      #pragma unroll
      for (int t=0; t<NTL; ++t){
        bf16x8 v = *(const bf16x8*)(As + rb0 + offr + t*RSTRIDE17 + kb*32);
        __builtin_amdgcn_s_setprio(1);
        acc[0][t] = mfma16(w[0], v, acc[0][t]);
        acc[1][t] = mfma16(w[1], v, acc[1][t]);
        acc[2][t] = mfma16(w[2], v, acc[2][t]);
        acc[3][t] = mfma16(w[3], v, acc[3][t]);
        acc[4][t] = mfma16(w[4], v, acc[4][t]);
        acc[5][t] = mfma16(w[5], v, acc[5][t]);
        acc[6][t] = mfma16(w[6], v, acc[6][t]);
        acc[7][t] = mfma16(w[7], v, acc[7][t]);
        __builtin_amdgcn_s_setprio(0);
      }
    }
  }
}

// ---- after barrier: capture residual, write silu(dconv) in place, pw in place + resid ----
template<int NTL>
__device__ __forceinline__ void pwres_phase(f32x4 (&acc)[8][2],
    u16* __restrict__ As, const u16* __restrict__ wpw,
    const float* __restrict__ bp, int lane, int T0)
{
  const int col = lane & 15, kg = lane >> 4;
  const int rb0 = ((T0+1)*17 + col + 1)*ROWP;
  uint4 rsd[NTL][4];
  #pragma unroll
  for (int t=0;t<NTL;++t){
    const u16* rp = As + rb0 + t*RSTRIDE17 + kg*16;
    rsd[t][0] = *(const uint4*)rp;
    rsd[t][1] = *(const uint4*)(rp + 8);
    rsd[t][2] = *(const uint4*)(rp + 64);
    rsd[t][3] = *(const uint4*)(rp + 72);
  }
  #pragma unroll
  for (int t=0;t<NTL;++t){
    if (col < 15){
      u16* dp = As + rb0 + t*RSTRIDE17 + kg*16;
      *(uint4*)dp      = pack_silu2(acc[0][t], acc[1][t]);
      *(uint4*)(dp+8)  = pack_silu2(acc[2][t], acc[3][t]);
      *(uint4*)(dp+64) = pack_silu2(acc[4][t], acc[5][t]);
      *(uint4*)(dp+72) = pack_silu2(acc[6][t], acc[7][t]);
    }
  }
  #pragma unroll
  for (int t=0;t<NTL;++t){
    f32x4 a[8];
    #pragma unroll
    for (int ot=0;ot<8;++ot) a[ot] = *(const f32x4*)(bp + ot*16 + kg*4);
    const u16* srow = As + rb0 + t*RSTRIDE17 + kg*8;
    #pragma unroll 1
    for (int kb=0; kb<4; ++kb){
      bf16x8 w[8];
      #pragma unroll
      for (int ot=0; ot<8; ++ot)
        w[ot] = *(const bf16x8*)(wpw + (kb*8 + ot)*512 + lane*8);
      bf16x8 v = *(const bf16x8*)(srow + kb*32);
      __builtin_amdgcn_s_setprio(1);
      a[0] = mfma16(w[0], v, a[0]); a[1] = mfma16(w[1], v, a[1]);
      a[2] = mfma16(w[2], v, a[2]); a[3] = mfma16(w[3], v, a[3]);
      a[4] = mfma16(w[4], v, a[4]); a[5] = mfma16(w[5], v, a[5]);
      a[6] = mfma16(w[6], v, a[6]); a[7] = mfma16(w[7], v, a[7]);
      __builtin_amdgcn_s_setprio(0);
    }
    if (col < 15){
      u16* dp = As + rb0 + t*RSTRIDE17 + kg*16;
      *(uint4*)dp      = silu_add4(a[0], a[1], rsd[t][0]);
      *(uint4*)(dp+8)  = silu_add4(a[2], a[3], rsd[t][1]);
      *(uint4*)(dp+64) = silu_add4(a[4], a[5], rsd[t][2]);
      *(uint4*)(dp+72) = silu_add4(a[6], a[7], rsd[t][3]);
    }
  }
}

// ---- tail: c1 (no resid), c2 (+resid), final 128->64 to global; all same-wave, no barriers ----
template<int NTL>
__device__ __forceinline__ void tail_phase(u16* __restrict__ As,
    const u16* __restrict__ w1, const u16* __restrict__ w2, const u16* __restrict__ wf,
    const float* __restrict__ b1, const float* __restrict__ b2, const float* __restrict__ bf,
    float* __restrict__ out, int lane, int T0, int bd)
{
  const int col = lane & 15, kg = lane >> 4;
  const int rb0 = ((T0+1)*17 + col + 1)*ROWP;
  uint4 rsd[NTL][4];
  #pragma unroll
  for (int t=0;t<NTL;++t){
    const u16* rp = As + rb0 + t*RSTRIDE17 + kg*16;
    rsd[t][0] = *(const uint4*)rp;
    rsd[t][1] = *(const uint4*)(rp + 8);
    rsd[t][2] = *(const uint4*)(rp + 64);
    rsd[t][3] = *(const uint4*)(rp + 72);
  }
  // c1
  #pragma unroll
  for (int t=0;t<NTL;++t){
    f32x4 a[8];
    #pragma unroll
    for (int ot=0;ot<8;++ot) a[ot] = *(const f32x4*)(b1 + ot*16 + kg*4);
    const u16* srow = As + rb0 + t*RSTRIDE17 + kg*8;
    #pragma unroll 1
    for (int kb=0; kb<4; ++kb){
      bf16x8 w[8];
      #pragma unroll
      for (int ot=0; ot<8; ++ot)
        w[ot] = *(const bf16x8*)(w1 + (kb*8 + ot)*512 + lane*8);
      bf16x8 v = *(const bf16x8*)(srow + kb*32);
      __builtin_amdgcn_s_setprio(1);
      a[0] = mfma16(w[0], v, a[0]); a[1] = mfma16(w[1], v, a[1]);
      a[2] = mfma16(w[2], v, a[2]); a[3] = mfma16(w[3], v, a[3]);
      a[4] = mfma16(w[4], v, a[4]); a[5] = mfma16(w[5], v, a[5]);
      a[6] = mfma16(w[6], v, a[6]); a[7] = mfma16(w[7], v, a[7]);
      __builtin_amdgcn_s_setprio(0);
    }
    if (col < 15){
      u16* dp = As + rb0 + t*RSTRIDE17 + kg*16;
      *(uint4*)dp      = pack_silu2(a[0], a[1]);
      *(uint4*)(dp+8)  = pack_silu2(a[2], a[3]);
      *(uint4*)(dp+64) = pack_silu2(a[4], a[5]);
      *(uint4*)(dp+72) = pack_silu2(a[6], a[7]);
    }
  }
  // c2 + resid
  #pragma unroll
  for (int t=0;t<NTL;++t){
    f32x4 a[8];
    #pragma unroll
    for (int ot=0;ot<8;++ot) a[ot] = *(const f32x4*)(b2 + ot*16 + kg*4);
    const u16* srow = As + rb0 + t*RSTRIDE17 + kg*8;
    #pragma unroll 1
    for (int kb=0; kb<4; ++kb){
      bf16x8 w[8];
      #pragma unroll
      for (int ot=0; ot<8; ++ot)
        w[ot] = *(const bf16x8*)(w2 + (kb*8 + ot)*512 + lane*8);
      bf16x8 v = *(const bf16x8*)(srow + kb*32);
      __builtin_amdgcn_s_setprio(1);
      a[0] = mfma16(w[0], v, a[0]); a[1] = mfma16(w[1], v, a[1]);
      a[2] = mfma16(w[2], v, a[2]); a[3] = mfma16(w[3], v, a[3]);
      a[4] = mfma16(w[4], v, a[4]); a[5] = mfma16(w[5], v, a[5]);
      a[6] = mfma16(w[6], v, a[6]); a[7] = mfma16(w[7], v, a[7]);
      __builtin_amdgcn_s_setprio(0);
    }
    if (col < 15){
      u16* dp = As + rb0 + t*RSTRIDE17 + kg*16;
      *(uint4*)dp      = silu_add4(a[0], a[1], rsd[t][0]);
      *(uint4*)(dp+8)  = silu_add4(a[2], a[3], rsd[t][1]);
      *(uint4*)(dp+64) = silu_add4(a[4], a[5], rsd[t][2]);
      *(uint4*)(dp+72) = silu_add4(a[6], a[7], rsd[t][3]);
    }
  }
  // final
  #pragma unroll
  for (int t=0;t<NTL;++t){
    f32x4 a4[4];
    #pragma unroll
    for (int ot=0;ot<4;++ot) a4[ot] = *(const f32x4*)(bf + ot*16 + kg*4);
    const u16* srow = As + rb0 + t*RSTRIDE17 + kg*8;
    #pragma unroll 1
    for (int kb=0; kb<4; ++kb){
      bf16x8 w[4];
      #pragma unroll
      for (int ot=0; ot<4; ++ot)
        w[ot] = *(const bf16x8*)(wf + (kb*4 + ot)*512 + lane*8);
      bf16x8 v = *(const bf16x8*)(srow + kb*32);
      __builtin_amdgcn_s_setprio(1);
      a4[0] = mfma16(w[0], v, a4[0]); a4[1] = mfma16(w[1], v, a4[1]);
      a4[2] = mfma16(w[2], v, a4[2]); a4[3] = mfma16(w[3], v, a4[3]);
      __builtin_amdgcn_s_setprio(0);
    }
    if (col < 15){
      #pragma unroll
      for (int ot=0; ot<4; ++ot){
        float* op = out + ((size_t)(bd*64 + ot*16 + kg*4))*NPOS + (T0+t)*15 + col;
        op[0]      = a4[ot][0];
        op[NPOS]   = a4[ot][1];
        op[2*NPOS] = a4[ot][2];
        op[3*NPOS] = a4[ot][3];
      }
    }
  }
}

__global__ void __launch_bounds__(512, 2)
mix9_main(const float* __restrict__ x,
          const float* __restrict__ b_rd,
          const float* __restrict__ b_rp,
          const float* __restrict__ b_c1,
          const float* __restrict__ b_c2,
          const float* __restrict__ b_fin,
          const float* __restrict__ wt,
          float* __restrict__ out)
{
  extern __shared__ u16 sm[];
  u16* As = sm;              // [289][136] haloed bf16 (stored-perm'd ch), zero halo; in-place all layers

  const int blk  = blockIdx.x;
  const int b    = blk >> 2, d = blk & 3;
  const int tid  = threadIdx.x;
  const int wave = __builtin_amdgcn_readfirstlane(tid >> 6);
  const int lane = tid & 63;
  const int T0   = 2*wave;            // wave 7 -> T0=14, NTL=1

  const int DI0[4] = {0,-1, 1,-1}, DJ0[4] = {-1, 0,-1,-1};
  const int DI2[4] = {0, 1,-1, 1}, DJ2[4] = { 1, 0, 1, 1};
  const int di0 = DI0[d], dj0 = DJ0[d], di2 = DI2[d], dj2 = DJ2[d];
  const int dr0 = di0*17 + dj0;
  const int dr2 = di2*17 + dj2;

  // zero haloed A; stage input into the tail region (disjoint from zeroed range)
  for (int k2 = tid; k2 < A_ELEMS; k2 += 512) As[k2] = 0;
  float* xs = (float*)(As + A_ELEMS);     // 512 floats
  if (tid < 450) xs[tid] = x[b*450 + tid];
  __syncthreads();

  // ---- dconv0: 2 -> 128 (plain VALU, fp32 stored-order weights) -> As ----
  {
    const float* b0p = wt + 768;
    const int ob = wave * 16;
    #pragma unroll 1
    for (int pb = 0; pb < 4; ++pb){
      int pp = pb*64 + lane;              // p' = i*16 + j
      int i = pp >> 4, j = pp & 15;
      if (i >= 15 || j >= 15) continue;
      float acc0[16];
      #pragma unroll
      for (int oo=0;oo<16;++oo) acc0[oo] = b0p[ob+oo];
      #pragma unroll
      for (int c=0;c<2;++c){
        int i0=i+di0, j0=j+dj0, i2=i+di2, j2=j+dj2;
        float x0 = ((unsigned)i0<15u && (unsigned)j0<15u) ? xs[c*NPOS + i0*15 + j0] : 0.f;
        float x1 = xs[c*NPOS + i*15 + j];
        float x2 = ((unsigned)i2<15u && (unsigned)j2<15u) ? xs[c*NPOS + i2*15 + j2] : 0.f;
        const float* w0r = wt + (c*3+0)*128 + ob;
        const float* w1r = wt + (c*3+1)*128 + ob;
        const float* w2r = wt + (c*3+2)*128 + ob;
        #pragma unroll
        for (int oo=0;oo<16;++oo)
          acc0[oo] = fmaf(w0r[oo],x0, fmaf(w1r[oo],x1, fmaf(w2r[oo],x2, acc0[oo])));
      }
      u16* dp = As + ((i+1)*17 + (j+1))*ROWP + ob;
      #pragma unroll
      for (int oo=0;oo<16;oo+=2)
        *(u32*)(dp+oo) = packbf(silu_f(acc0[oo]), silu_f(acc0[oo+1]));
    }
  }
  __syncthreads();

  const u16* wsb = (const u16*)(wt + 896);
  f32x4 acc[8][2];

  // ---- 4 directional res blocks: dconv -> BARRIER -> in-place write + pw ----
  #pragma unroll 1
  for (int L = 0; L < 4; ++L){
    if (wave < 7) dconv_phase<2>(acc, As, wsb + L*WA_PER_L, b_rd + L*128, lane, T0, dr0, dr2);
    else          dconv_phase<1>(acc, As, wsb + L*WA_PER_L, b_rd + L*128, lane, 14, dr0, dr2);
    __syncthreads();
    if (wave < 7) pwres_phase<2>(acc, As, wsb + WP_OFF + L*WP_PER, b_rp + L*128, lane, T0);
    else          pwres_phase<1>(acc, As, wsb + WP_OFF + L*WP_PER, b_rp + L*128, lane, 14);
    if (L < 3) __syncthreads();
  }

  // ---- Conv0d res block + final (own rows only; no barriers) ----
  if (wave < 7)
    tail_phase<2>(As, wsb + WP_OFF + 4*WP_PER, wsb + WP_OFF + 5*WP_PER, wsb + WF_OFF,
                  b_c1, b_c2, b_fin, out, lane, T0, b*4 + d);
  else
    tail_phase<1>(As, wsb + WP_OFF + 4*WP_PER, wsb + WP_OFF + 5*WP_PER, wsb + WF_OFF,
                  b_c1, b_c2, b_fin, out, lane, 14, b*4 + d);
}

extern "C" void kernel_launch(void* const* d_in, const int* in_sizes, int n_in,
                              void* d_out, int out_size, void* d_ws, size_t ws_size,
                              hipStream_t stream)
{
  const float* x     = (const float*)d_in[0];
  const float* w_d0  = (const float*)d_in[1];
  const float* b_d0  = (const float*)d_in[2];
  const float* w_rd  = (const float*)d_in[3];
  const float* b_rd  = (const float*)d_in[4];
  const float* w_rp  = (const float*)d_in[5];
  const float* b_rp  = (const float*)d_in[6];
  const float* w_c1  = (const float*)d_in[7];
  const float* b_c1  = (const float*)d_in[8];
  const float* w_c2  = (const float*)d_in[9];
  const float* b_c2  = (const float*)d_in[10];
  const float* w_fin = (const float*)d_in[11];
  const float* b_fin = (const float*)d_in[12];
  float* wt  = (float*)d_ws;
  float* out = (float*)d_out;

  prep_w<<<128, 512, 0, stream>>>(w_d0, b_d0, w_rd, w_rp, w_c1, w_c2, w_fin, wt);

  (void)hipFuncSetAttribute((const void*)mix9_main,
                            hipFuncAttributeMaxDynamicSharedMemorySize, LDS_BYTES);
  mix9_main<<<1024, 512, LDS_BYTES, stream>>>(x, b_rd, b_rp, b_c1, b_c2, b_fin, wt, out);
}

// Round 13
// 250.438 us; speedup vs baseline: 1.1417x; 1.1417x over previous
//
#include <hip/hip_runtime.h>

using u16 = unsigned short;
using u32 = unsigned int;

typedef __bf16 bf16x8 __attribute__((ext_vector_type(8)));
typedef float  f32x4  __attribute__((ext_vector_type(4)));
typedef float  f32x16 __attribute__((ext_vector_type(16)));

#define NPOS   225          // 15*15 valid positions
#define ROWP   136          // LDS row stride in ushorts (272B)
#define A_ROWS 289          // 17*17 haloed
#define B_ROWS 256          // p' = ptile*32 + p32, ptile 0..7
#define A_ELEMS (A_ROWS*ROWP)            // 39304 u16
#define B_ELEMS (B_ROWS*ROWP)            // 34816 u16
#define LDS_BYTES ((A_ELEMS + B_ELEMS)*2)  // 148240 B < 160 KiB

// ---- workspace layout ----
// floats [0..768): dconv0 weights [k=c*3+t][s_o] stored-order; [768..896): dconv0 bias stored
// bf16 (u16) region, offsets in u16 units:
#define WA_PER_L 49152      // per dconv layer: [tap 3][m 8][ot 4][lane 64][8]
#define WP_OFF   (4*WA_PER_L)          // 196608 ; 6 x [m 8][ot 4][lane 64][8]
#define WP_PER   16384
#define WF_OFF   (WP_OFF + 6*WP_PER)   // 294912 ; [m 8][ot 2][lane 64][8]
#define W_U16_TOTAL (WF_OFF + 8192)    // 303104

// stored slot s -> logical channel (within 32-ch tile): s=16h+4q+r -> c=4h+8q+r
__host__ __device__ __forceinline__ int chof(int c){
  int s = c & 31;
  return (c & ~31) | (((s >> 4) & 1)*4 + ((s >> 2) & 3)*8 + (s & 3));
}

__device__ __forceinline__ float bflo(u32 q){ return __uint_as_float(q << 16); }
__device__ __forceinline__ float bfhi(u32 q){ return __uint_as_float(q & 0xffff0000u); }
__device__ __forceinline__ u16 f2bf(float f){
  u32 u = __float_as_uint(f);
  return (u16)((u + 0x7fffu + ((u >> 16) & 1u)) >> 16);   // RNE (prep kernel only)
}
__device__ __forceinline__ u32 packbf(float a, float b){
  union { __bf16 h[2]; u32 u; } r;
  r.h[0] = (__bf16)a; r.h[1] = (__bf16)b;
  return r.u;
}
__device__ __forceinline__ float silu_f(float x){
  return x * __builtin_amdgcn_rcpf(1.f + __expf(-x));
}
__device__ __forceinline__ f32x16 mfma32(bf16x8 a, bf16x8 b, f32x16 c){
  return __builtin_amdgcn_mfma_f32_32x32x16_bf16(a, b, c, 0, 0, 0);
}

// silu+pack 16 accs -> 2 uint4 (stored slots 16h..16h+15 == reg order)
__device__ __forceinline__ void pack16(const f32x16& a, uint4& lo, uint4& hi){
  lo.x = packbf(silu_f(a[0]),  silu_f(a[1]));
  lo.y = packbf(silu_f(a[2]),  silu_f(a[3]));
  lo.z = packbf(silu_f(a[4]),  silu_f(a[5]));
  lo.w = packbf(silu_f(a[6]),  silu_f(a[7]));
  hi.x = packbf(silu_f(a[8]),  silu_f(a[9]));
  hi.y = packbf(silu_f(a[10]), silu_f(a[11]));
  hi.z = packbf(silu_f(a[12]), silu_f(a[13]));
  hi.w = packbf(silu_f(a[14]), silu_f(a[15]));
}
__device__ __forceinline__ void pack16r(const f32x16& a, const uint4& r0, const uint4& r1,
                                        uint4& lo, uint4& hi){
  lo.x = packbf(silu_f(a[0])  + bflo(r0.x), silu_f(a[1])  + bfhi(r0.x));
  lo.y = packbf(silu_f(a[2])  + bflo(r0.y), silu_f(a[3])  + bfhi(r0.y));
  lo.z = packbf(silu_f(a[4])  + bflo(r0.z), silu_f(a[5])  + bfhi(r0.z));
  lo.w = packbf(silu_f(a[6])  + bflo(r0.w), silu_f(a[7])  + bfhi(r0.w));
  hi.x = packbf(silu_f(a[8])  + bflo(r1.x), silu_f(a[9])  + bfhi(r1.x));
  hi.y = packbf(silu_f(a[10]) + bflo(r1.y), silu_f(a[11]) + bfhi(r1.y));
  hi.z = packbf(silu_f(a[12]) + bflo(r1.z), silu_f(a[13]) + bfhi(r1.z));
  hi.w = packbf(silu_f(a[14]) + bflo(r1.w), silu_f(a[15]) + bfhi(r1.w));
}

// ---- weight prep (32x32 fragments; k-dim indexed by STORED channel via chof) ----
__global__ void prep_w(const float* __restrict__ d0w, const float* __restrict__ d0b,
                       const float* __restrict__ rdw,
                       const float* __restrict__ rpw, const float* __restrict__ c1w,
                       const float* __restrict__ c2w, const float* __restrict__ fw,
                       float* __restrict__ ws)
{
  u16* wsb = (u16*)(ws + 896);
  const int total = 896 + W_U16_TOTAL;
  for (int idx = blockIdx.x*blockDim.x + threadIdx.x; idx < total; idx += gridDim.x*blockDim.x){
    if (idx < 768){                      // dconv0: ws[k*128+s] = w[chof(s)][k]
      int k = idx >> 7, s = idx & 127;
      ws[idx] = d0w[chof(s)*6 + k];
      continue;
    }
    if (idx < 896){
      int s = idx - 768;
      ws[idx] = d0b[chof(s)];
      continue;
    }
    int e = idx - 896;
    float v;
    if (e < WP_OFF){                     // dconv frags [L][tap][m][ot][l][j]
      int L = e / WA_PER_L, r = e % WA_PER_L;
      int tap = r / 16384, r1 = r % 16384;
      int m = r1 >> 11, r2 = r1 & 2047;
      int ot = r2 >> 9, l = (r2 >> 3) & 63, j = r2 & 7;
      int o = ot*32 + (l & 31);
      int ck = chof(m*16 + ((l >> 5) << 3) + j);
      v = rdw[((L*128 + o)*128 + ck)*3 + tap];
    } else if (e < WF_OFF){              // pw frags [i6][m][ot][l][j]
      int t2 = e - WP_OFF;
      int i = t2 / WP_PER, r = t2 % WP_PER;
      int m = r >> 11, ot = (r >> 9) & 3, l = (r >> 3) & 63, j = r & 7;
      int o = ot*32 + (l & 31);
      int ck = chof(m*16 + ((l >> 5) << 3) + j);
      v = (i < 4) ? rpw[(i*128 + o)*128 + ck]
        : (i == 4) ? c1w[o*128 + ck] : c2w[o*128 + ck];
    } else {                             // final frags [m][ot2][l][j]
      int e2 = e - WF_OFF;
      int m = e2 >> 10, ot = (e2 >> 9) & 1, l = (e2 >> 3) & 63, j = e2 & 7;
      int o = ot*32 + (l & 31);
      int ck = chof(m*16 + ((l >> 5) << 3) + j);
      v = fw[o*128 + ck];
    }
    wsb[e] = f2bf(v);
  }
}

__device__ __forceinline__ f32x16 bias16(const float* bb){
  f32x16 bz;
  #pragma unroll
  for (int q=0;q<4;++q){
    f32x4 b4 = *(const f32x4*)(bb + 8*q);
    bz[4*q] = b4[0]; bz[4*q+1] = b4[1]; bz[4*q+2] = b4[2]; bz[4*q+3] = b4[3];
  }
  return bz;
}

// ---- directional conv 128->128, 32x32 MFMA: A(haloed) -> B(compact) ----
// wave: og (2 o-tiles of 32), pg (2 p-tiles of 32 positions = 2 row-pairs)
__device__ __forceinline__ void dconv32(const u16* __restrict__ As, u16* __restrict__ Bs,
    const u16* __restrict__ wl, const float* __restrict__ bias,
    int lane, int og, int pg, int dr0, int dr2)
{
  const int p32 = lane & 31, h = lane >> 5;
  f32x16 acc[2][2];
  #pragma unroll
  for (int o2=0;o2<2;++o2){
    f32x16 bz = bias16(bias + (2*og+o2)*32 + 4*h);
    acc[o2][0] = bz; acc[o2][1] = bz;
  }
  int base[2];
  #pragma unroll
  for (int t=0;t<2;++t){
    int i = (pg*2+t)*2 + (p32 >> 4), j = p32 & 15;
    base[t] = ((i+1)*17 + (j+1))*ROWP + h*8;
  }
  #pragma unroll 1
  for (int tap=0; tap<3; ++tap){
    const int droff = ((tap==0) ? dr0 : (tap==1) ? 0 : dr2)*ROWP;
    bf16x8 w0[8], w1[8];
    #pragma unroll
    for (int m=0;m<8;++m){
      w0[m] = *(const bf16x8*)(wl + tap*16384 + m*2048 + (2*og  )*512 + lane*8);
      w1[m] = *(const bf16x8*)(wl + tap*16384 + m*2048 + (2*og+1)*512 + lane*8);
    }
    #pragma unroll
    for (int m=0;m<8;++m){
      #pragma unroll
      for (int t=0;t<2;++t){
        bf16x8 v = *(const bf16x8*)(As + base[t] + droff + m*16);
        __builtin_amdgcn_s_setprio(1);
        acc[0][t] = mfma32(w0[m], v, acc[0][t]);
        acc[1][t] = mfma32(w1[m], v, acc[1][t]);
        __builtin_amdgcn_s_setprio(0);
      }
    }
  }
  #pragma unroll
  for (int t=0;t<2;++t){
    int pp = (pg*2+t)*32 + p32;
    #pragma unroll
    for (int o2=0;o2<2;++o2){
      u16* dp = Bs + pp*ROWP + (2*og+o2)*32 + 16*h;
      uint4 lo, hi; pack16(acc[o2][t], lo, hi);
      *(uint4*)dp = lo; *(uint4*)(dp+8) = hi;   // garbage rows (j==15/i==15) harmless
    }
  }
}

// ---- pointwise 128->128, 32x32 MFMA ----
template<bool SRC_HALO, bool DST_HALO, bool RESID>
__device__ __forceinline__ void pw32(const u16* __restrict__ src, u16* __restrict__ dst,
    const u16* __restrict__ wl, const float* __restrict__ bias,
    int lane, int og, int pg)
{
  const int p32 = lane & 31, h = lane >> 5;
  f32x16 acc[2][2];
  #pragma unroll
  for (int o2=0;o2<2;++o2){
    f32x16 bz = bias16(bias + (2*og+o2)*32 + 4*h);
    acc[o2][0] = bz; acc[o2][1] = bz;
  }
  bf16x8 w0[8], w1[8];
  #pragma unroll
  for (int m=0;m<8;++m){
    w0[m] = *(const bf16x8*)(wl + m*2048 + (2*og  )*512 + lane*8);
    w1[m] = *(const bf16x8*)(wl + m*2048 + (2*og+1)*512 + lane*8);
  }
  int rsrc[2], rdst[2], valid[2];
  #pragma unroll
  for (int t=0;t<2;++t){
    int i = (pg*2+t)*2 + (p32 >> 4), j = p32 & 15;
    int r17 = ((i+1)*17 + (j+1))*ROWP;
    int rc  = ((pg*2+t)*32 + p32)*ROWP;
    rsrc[t] = SRC_HALO ? r17 : rc;
    rdst[t] = DST_HALO ? r17 : rc;
    valid[t] = (j < 15) && (i < 15);
  }
  #pragma unroll
  for (int m=0;m<8;++m){
    #pragma unroll
    for (int t=0;t<2;++t){
      bf16x8 v = *(const bf16x8*)(src + rsrc[t] + h*8 + m*16);
      __builtin_amdgcn_s_setprio(1);
      acc[0][t] = mfma32(w0[m], v, acc[0][t]);
      acc[1][t] = mfma32(w1[m], v, acc[1][t]);
      __builtin_amdgcn_s_setprio(0);
    }
  }
  #pragma unroll
  for (int t=0;t<2;++t){
    if (!DST_HALO || valid[t]){
      #pragma unroll
      for (int o2=0;o2<2;++o2){
        u16* dp = dst + rdst[t] + (2*og+o2)*32 + 16*h;
        uint4 lo, hi;
        if (RESID){
          uint4 r0 = *(const uint4*)dp;
          uint4 r1 = *(const uint4*)(dp+8);
          pack16r(acc[o2][t], r0, r1, lo, hi);
        } else {
          pack16(acc[o2][t], lo, hi);
        }
        *(uint4*)dp = lo; *(uint4*)(dp+8) = hi;
      }
    }
  }
}

// ---- final 1x1 128->64, 32x32 MFMA; wave owns 1 o-tile (32 ch), 2 p-tiles ----
__device__ __forceinline__ void fin32(const u16* __restrict__ As,
    const u16* __restrict__ wl, const float* __restrict__ bias,
    float* __restrict__ out, int lane, int og, int pg, int bd)
{
  const int p32 = lane & 31, h = lane >> 5;
  f32x16 bz = bias16(bias + og*32 + 4*h);
  f32x16 acc[2] = {bz, bz};
  bf16x8 wf[8];
  #pragma unroll
  for (int m=0;m<8;++m)
    wf[m] = *(const bf16x8*)(wl + m*1024 + og*512 + lane*8);
  int base[2], ii[2], jj[2];
  #pragma unroll
  for (int t=0;t<2;++t){
    ii[t] = (pg*2+t)*2 + (p32 >> 4); jj[t] = p32 & 15;
    base[t] = ((ii[t]+1)*17 + (jj[t]+1))*ROWP + h*8;
  }
  #pragma unroll
  for (int m=0;m<8;++m){
    #pragma unroll
    for (int t=0;t<2;++t){
      bf16x8 v = *(const bf16x8*)(As + base[t] + m*16);
      __builtin_amdgcn_s_setprio(1);
      acc[t] = mfma32(wf[m], v, acc[t]);
      __builtin_amdgcn_s_setprio(0);
    }
  }
  #pragma unroll
  for (int t=0;t<2;++t){
    if (jj[t] < 15 && ii[t] < 15){
      #pragma unroll
      for (int q=0;q<4;++q){
        #pragma unroll
        for (int r=0;r<4;++r){
          int ch = og*32 + 4*h + 8*q + r;
          out[((size_t)(bd*64 + ch))*NPOS + ii[t]*15 + jj[t]] = acc[t][4*q+r];
        }
      }
    }
  }
}

__global__ void __launch_bounds__(512, 2)
mix9_main(const float* __restrict__ x,
          const float* __restrict__ b_rd,
          const float* __restrict__ b_rp,
          const float* __restrict__ b_c1,
          const float* __restrict__ b_c2,
          const float* __restrict__ b_fin,
          const float* __restrict__ wt,
          float* __restrict__ out)
{
  extern __shared__ u16 sm[];
  u16* As = sm;              // [289][136] haloed bf16 (stored-perm ch), zero halo
  u16* Bs = sm + A_ELEMS;    // [256][136] compact p'-rows (stored-perm ch)

  const int blk  = blockIdx.x;
  const int b    = blk >> 2, d = blk & 3;
  const int tid  = threadIdx.x;
  const int wave = __builtin_amdgcn_readfirstlane(tid >> 6);   // 0..7
  const int lane = tid & 63;
  const int og   = wave >> 2;        // 2 o-groups
  const int pg   = wave & 3;         // 4 p-groups (2 p-tiles each)

  const int DI0[4] = {0,-1, 1,-1}, DJ0[4] = {-1, 0,-1,-1};
  const int DI2[4] = {0, 1,-1, 1}, DJ2[4] = { 1, 0, 1, 1};
  const int di0 = DI0[d], dj0 = DJ0[d], di2 = DI2[d], dj2 = DJ2[d];
  const int dr0 = di0*17 + dj0;
  const int dr2 = di2*17 + dj2;

  // zero haloed A; stage input image into B-region as fp32
  for (int k2 = tid; k2 < A_ELEMS; k2 += 512) As[k2] = 0;
  float* xs = (float*)Bs;          // 450 floats
  if (tid < 450) xs[tid] = x[b*450 + tid];
  __syncthreads();

  // ---- dconv0: 2 -> 128 (plain VALU, stored-order weights) -> A ----
  {
    const float* b0p = wt + 768;
    const int ob = wave * 16;
    #pragma unroll 1
    for (int pb = 0; pb < 4; ++pb){
      int pp = pb*64 + lane;              // p' = i*16 + j
      int i = pp >> 4, j = pp & 15;
      if (i >= 15 || j >= 15) continue;
      float acc0[16];
      #pragma unroll
      for (int oo=0;oo<16;++oo) acc0[oo] = b0p[ob+oo];
      #pragma unroll
      for (int c=0;c<2;++c){
        int i0=i+di0, j0=j+dj0, i2=i+di2, j2=j+dj2;
        float x0 = ((unsigned)i0<15u && (unsigned)j0<15u) ? xs[c*NPOS + i0*15 + j0] : 0.f;
        float x1 = xs[c*NPOS + i*15 + j];
        float x2 = ((unsigned)i2<15u && (unsigned)j2<15u) ? xs[c*NPOS + i2*15 + j2] : 0.f;
        const float* w0r = wt + (c*3+0)*128 + ob;
        const float* w1r = wt + (c*3+1)*128 + ob;
        const float* w2r = wt + (c*3+2)*128 + ob;
        #pragma unroll
        for (int oo=0;oo<16;++oo)
          acc0[oo] = fmaf(w0r[oo],x0, fmaf(w1r[oo],x1, fmaf(w2r[oo],x2, acc0[oo])));
      }
      u16* dp = As + ((i+1)*17 + (j+1))*ROWP + ob;
      #pragma unroll
      for (int oo=0;oo<16;oo+=2)
        *(u32*)(dp+oo) = packbf(silu_f(acc0[oo]), silu_f(acc0[oo+1]));
    }
  }
  __syncthreads();

  const u16* wsb = (const u16*)(wt + 896);

  // ---- 4 directional res blocks ----
  #pragma unroll 1
  for (int L = 0; L < 4; ++L){
    dconv32(As, Bs, wsb + L*WA_PER_L, b_rd + L*128, lane, og, pg, dr0, dr2);
    __syncthreads();
    pw32<false,true,true>(Bs, As, wsb + WP_OFF + L*WP_PER, b_rp + L*128, lane, og, pg);
    __syncthreads();
  }

  // ---- Conv0d res block ----
  pw32<true,false,false>(As, Bs, wsb + WP_OFF + 4*WP_PER, b_c1, lane, og, pg);
  __syncthreads();
  pw32<false,true,true>(Bs, As, wsb + WP_OFF + 5*WP_PER, b_c2, lane, og, pg);
  __syncthreads();

  // ---- final 1x1: 128 -> 64 ----
  fin32(As, wsb + WF_OFF, b_fin, out, lane, og, pg, b*4 + d);
}

extern "C" void kernel_launch(void* const* d_in, const int* in_sizes, int n_in,
                              void* d_out, int out_size, void* d_ws, size_t ws_size,
                              hipStream_t stream)
{
  const float* x     = (const float*)d_in[0];
  const float* w_d0  = (const float*)d_in[1];
  const float* b_d0  = (const float*)d_in[2];
  const float* w_rd  = (const float*)d_in[3];
  const float* b_rd  = (const float*)d_in[4];
  const float* w_rp  = (const float*)d_in[5];
  const float* b_rp  = (const float*)d_in[6];
  const float* w_c1  = (const float*)d_in[7];
  const float* b_c1  = (const float*)d_in[8];
  const float* w_c2  = (const float*)d_in[9];
  const float* b_c2  = (const float*)d_in[10];
  const float* w_fin = (const float*)d_in[11];
  const float* b_fin = (const float*)d_in[12];
  float* wt  = (float*)d_ws;
  float* out = (float*)d_out;

  prep_w<<<128, 512, 0, stream>>>(w_d0, b_d0, w_rd, w_rp, w_c1, w_c2, w_fin, wt);

  (void)hipFuncSetAttribute((const void*)mix9_main,
                            hipFuncAttributeMaxDynamicSharedMemorySize, LDS_BYTES);
  mix9_main<<<1024, 512, LDS_BYTES, stream>>>(x, b_rd, b_rp, b_c1, b_c2, b_fin, wt, out);
}